// Round 1
// baseline (170.246 us; speedup 1.0000x reference)
//
#include <hip/hip_runtime.h>
#include <hip/hip_bf16.h>
#include <float.h>

#define DEPTH_PARAM 0.5f
#define LENGTH_PENALTY 1.5f

__global__ void init_out_kernel(float* out) {
    out[0] = 0.0f;
}

// One block per batch row. Computes argmax(y_pred[b]), argmax(y_true[b]) via
// float4 scan + shuffle reduction, then thread 0 does the tiny hierarchical
// loss tail and atomicAdds total/B into out[0].
__global__ __launch_bounds__(256) void hier_loss_kernel(
    const float* __restrict__ y_pred,
    const float* __restrict__ y_true,
    const float* __restrict__ class_weights,
    const int* __restrict__ path_ids,
    const int* __restrict__ path_len,
    const int* __restrict__ sib_start,
    const int* __restrict__ sib_size,
    float* __restrict__ out,
    int C, int D, int Bsz)
{
    const int b = blockIdx.x;
    const int tid = threadIdx.x;
    const float* __restrict__ yp = y_pred + (size_t)b * C;
    const float* __restrict__ yt = y_true + (size_t)b * C;

    // ---- vectorized per-thread argmax over both rows ----
    float bp = -FLT_MAX; int bip = 0;   // y_pred best
    float bt = -FLT_MAX; int bit_ = 0;  // y_true best
    const int C4 = C >> 2;              // 2728/4 = 682, exact
    const float4* __restrict__ yp4 = (const float4*)yp;
    const float4* __restrict__ yt4 = (const float4*)yt;

    for (int i = tid; i < C4; i += blockDim.x) {
        float4 v = yp4[i];
        float4 w = yt4[i];
        int base = i << 2;
        // strict > keeps first occurrence (indices increase within thread)
        if (v.x > bp) { bp = v.x; bip = base + 0; }
        if (v.y > bp) { bp = v.y; bip = base + 1; }
        if (v.z > bp) { bp = v.z; bip = base + 2; }
        if (v.w > bp) { bp = v.w; bip = base + 3; }
        if (w.x > bt) { bt = w.x; bit_ = base + 0; }
        if (w.y > bt) { bt = w.y; bit_ = base + 1; }
        if (w.z > bt) { bt = w.z; bit_ = base + 2; }
        if (w.w > bt) { bt = w.w; bit_ = base + 3; }
    }
    // scalar remainder (C%4==0 for this problem, but be safe)
    for (int c = (C4 << 2) + tid; c < C; c += blockDim.x) {
        float v = yp[c]; if (v > bp) { bp = v; bip = c; }
        float w = yt[c]; if (w > bt) { bt = w; bit_ = c; }
    }

    // ---- wave (64-lane) shuffle reduction, tie-break smaller index ----
    for (int off = 32; off > 0; off >>= 1) {
        float ov = __shfl_down(bp, off); int oi = __shfl_down(bip, off);
        if (ov > bp || (ov == bp && oi < bip)) { bp = ov; bip = oi; }
        float ow = __shfl_down(bt, off); int oj = __shfl_down(bit_, off);
        if (ow > bt || (ow == bt && oj < bit_)) { bt = ow; bit_ = oj; }
    }

    __shared__ float s_val[2][4];
    __shared__ int   s_idx[2][4];
    const int lane = tid & 63;
    const int wid = tid >> 6;
    if (lane == 0) {
        s_val[0][wid] = bp;  s_idx[0][wid] = bip;
        s_val[1][wid] = bt;  s_idx[1][wid] = bit_;
    }
    __syncthreads();

    if (tid == 0) {
        const int nw = (blockDim.x + 63) >> 6;
        for (int w = 1; w < nw; w++) {
            float v = s_val[0][w]; int i0 = s_idx[0][w];
            if (v > bp || (v == bp && i0 < bip)) { bp = v; bip = i0; }
            float u = s_val[1][w]; int i1 = s_idx[1][w];
            if (u > bt || (u == bt && i1 < bit_)) { bt = u; bit_ = i1; }
        }
        const int pred_top = bip;
        const int true_top = bit_;
        const int lp = path_len[pred_top];
        const int lt = path_len[true_top];
        const int lmin = lp < lt ? lp : lt;

        float local = 0.0f;
        for (int l = 0; l < lmin; l++) {
            const int tix = path_ids[true_top * D + l];
            const int st  = sib_start[true_top * D + l];
            const int sz  = sib_size[true_top * D + l];
            // logits = y_pred * {0,1} mask -> masked-out entries contribute exp(0)=1
            float s = (float)(C - sz);
            for (int c = st; c < st + sz; c++) {
                s += expf(yp[c]);
            }
            const float lse = logf(s);
            const float ce = lse - yp[tix];
            const float lw = expf(-DEPTH_PARAM * (float)(lt - l - 1));
            local += lw * ce;
        }
        const float diff = fabsf((float)(lp - lt));
        const float total = local * (LENGTH_PENALTY * diff) * class_weights[true_top];
        atomicAdd(out, total / (float)Bsz);
    }
}

extern "C" void kernel_launch(void* const* d_in, const int* in_sizes, int n_in,
                              void* d_out, int out_size, void* d_ws, size_t ws_size,
                              hipStream_t stream) {
    const float* y_pred        = (const float*)d_in[0];
    const float* y_true        = (const float*)d_in[1];
    const float* class_weights = (const float*)d_in[2];
    const int*   path_ids      = (const int*)d_in[3];
    const int*   path_len      = (const int*)d_in[4];
    const int*   sib_start     = (const int*)d_in[5];
    const int*   sib_size      = (const int*)d_in[6];
    float* out = (float*)d_out;

    const int C = in_sizes[2];            // 2728
    const int D = in_sizes[3] / C;        // 5
    const int B = in_sizes[0] / C;        // 4096

    init_out_kernel<<<1, 1, 0, stream>>>(out);
    hier_loss_kernel<<<B, 256, 0, stream>>>(
        y_pred, y_true, class_weights, path_ids, path_len,
        sib_start, sib_size, out, C, D, B);
}

// Round 2
// 122.850 us; speedup vs baseline: 1.3858x; 1.3858x over previous
//
#include <hip/hip_runtime.h>
#include <hip/hip_bf16.h>
#include <float.h>

#define DEPTH_PARAM 0.5f
#define LENGTH_PENALTY 1.5f

// One WAVE (64 lanes) per batch row. Dual argmax via float4 scan + butterfly
// shuffle reduce (all lanes end with the result), then lanes 0..lmin-1 each
// compute one level's masked logsumexp in parallel. Per-row total -> ws.
__global__ __launch_bounds__(256) void hier_row_kernel(
    const float* __restrict__ y_pred,
    const float* __restrict__ y_true,
    const float* __restrict__ class_weights,
    const int* __restrict__ path_ids,
    const int* __restrict__ path_len,
    const int* __restrict__ sib_start,
    const int* __restrict__ sib_size,
    float* __restrict__ row_total,
    int C, int D, int Bsz)
{
    const int wid  = threadIdx.x >> 6;
    const int lane = threadIdx.x & 63;
    const int row  = blockIdx.x * 4 + wid;
    if (row >= Bsz) return;

    const float* __restrict__ yp = y_pred + (size_t)row * C;
    const float* __restrict__ yt = y_true + (size_t)row * C;

    // ---- vectorized dual argmax ----
    float bp = -FLT_MAX; int bip = 0;
    float bt = -FLT_MAX; int bit_ = 0;
    const int C4 = C >> 2;                    // 2728/4 = 682
    const float4* __restrict__ yp4 = (const float4*)yp;
    const float4* __restrict__ yt4 = (const float4*)yt;

    for (int i = lane; i < C4; i += 64) {
        float4 v = yp4[i];
        float4 w = yt4[i];
        int base = i << 2;
        if (v.x > bp) { bp = v.x; bip = base + 0; }
        if (v.y > bp) { bp = v.y; bip = base + 1; }
        if (v.z > bp) { bp = v.z; bip = base + 2; }
        if (v.w > bp) { bp = v.w; bip = base + 3; }
        if (w.x > bt) { bt = w.x; bit_ = base + 0; }
        if (w.y > bt) { bt = w.y; bit_ = base + 1; }
        if (w.z > bt) { bt = w.z; bit_ = base + 2; }
        if (w.w > bt) { bt = w.w; bit_ = base + 3; }
    }
    for (int c = (C4 << 2) + lane; c < C; c += 64) {
        float v = yp[c]; if (v > bp) { bp = v; bip = c; }
        float w = yt[c]; if (w > bt) { bt = w; bit_ = c; }
    }

    // ---- butterfly reduce: every lane ends with global (max, min-index) ----
    for (int m = 1; m < 64; m <<= 1) {
        float ov = __shfl_xor(bp, m); int oi = __shfl_xor(bip, m);
        if (ov > bp || (ov == bp && oi < bip)) { bp = ov; bip = oi; }
        float ow = __shfl_xor(bt, m); int oj = __shfl_xor(bit_, m);
        if (ow > bt || (ow == bt && oj < bit_)) { bt = ow; bit_ = oj; }
    }
    const int pred_top = bip;
    const int true_top = bit_;

    const int lp = path_len[pred_top];
    const int lt = path_len[true_top];
    const int lmin = lp < lt ? lp : lt;

    // ---- lane l handles level l (lmin <= 5) ----
    float contrib = 0.0f;
    if (lane < lmin) {
        const int l   = lane;
        const int tix = path_ids[true_top * D + l];
        const int st  = sib_start[true_top * D + l];
        const int sz  = sib_size[true_top * D + l];
        // logits = y_pred * {0,1}: masked-out entries contribute exp(0)=1
        float s = (float)(C - sz);
        for (int c = st; c < st + sz; c++) s += expf(yp[c]);
        const float ce = logf(s) - yp[tix];
        const float lw = expf(-DEPTH_PARAM * (float)(lt - l - 1));
        contrib = lw * ce;
    }
    // sum over lanes 0..7 (only 0..lmin-1 nonzero)
    for (int m = 1; m < 8; m <<= 1) contrib += __shfl_xor(contrib, m);

    if (lane == 0) {
        const float diff = fabsf((float)(lp - lt));
        row_total[row] = contrib * (LENGTH_PENALTY * diff) * class_weights[true_top];
    }
}

// Deterministic final sum: one block reduces all row totals, writes mean.
__global__ __launch_bounds__(256) void final_reduce_kernel(
    const float* __restrict__ row_total, float* __restrict__ out, int Bsz)
{
    const int tid = threadIdx.x;
    float s = 0.0f;
    for (int i = tid; i < Bsz; i += 256) s += row_total[i];
    for (int m = 1; m < 64; m <<= 1) s += __shfl_xor(s, m);

    __shared__ float sw[4];
    const int lane = tid & 63, wid = tid >> 6;
    if (lane == 0) sw[wid] = s;
    __syncthreads();
    if (tid == 0) {
        float t = sw[0] + sw[1] + sw[2] + sw[3];
        out[0] = t / (float)Bsz;
    }
}

extern "C" void kernel_launch(void* const* d_in, const int* in_sizes, int n_in,
                              void* d_out, int out_size, void* d_ws, size_t ws_size,
                              hipStream_t stream) {
    const float* y_pred        = (const float*)d_in[0];
    const float* y_true        = (const float*)d_in[1];
    const float* class_weights = (const float*)d_in[2];
    const int*   path_ids      = (const int*)d_in[3];
    const int*   path_len      = (const int*)d_in[4];
    const int*   sib_start     = (const int*)d_in[5];
    const int*   sib_size      = (const int*)d_in[6];
    float* out = (float*)d_out;
    float* row_total = (float*)d_ws;   // B floats

    const int C = in_sizes[2];            // 2728
    const int D = in_sizes[3] / C;        // 5
    const int B = in_sizes[0] / C;        // 4096

    const int grid = (B + 3) / 4;         // 4 waves/block, 1 wave/row
    hier_row_kernel<<<grid, 256, 0, stream>>>(
        y_pred, y_true, class_weights, path_ids, path_len,
        sib_start, sib_size, row_total, C, D, B);
    final_reduce_kernel<<<1, 256, 0, stream>>>(row_total, out, B);
}

// Round 3
// 120.210 us; speedup vs baseline: 1.4162x; 1.0220x over previous
//
#include <hip/hip_runtime.h>
#include <hip/hip_bf16.h>
#include <float.h>

#define DEPTH_PARAM 0.5f
#define LENGTH_PENALTY 1.5f

// TWO waves per batch row (256-thread block = 4 waves = 2 rows).
// Each wave scans half the row's float4s (interleaved stride-128), the two
// halves merge via LDS, then the first wave of the pair computes the tail
// with one lane-group of 8 per tree level (1 load + 1 expf per lane).
__global__ __launch_bounds__(256) void hier_row_kernel(
    const float* __restrict__ y_pred,
    const float* __restrict__ y_true,
    const float* __restrict__ class_weights,
    const int* __restrict__ path_ids,
    const int* __restrict__ path_len,
    const int* __restrict__ sib_start,
    const int* __restrict__ sib_size,
    float* __restrict__ row_total,
    int C, int D, int Bsz)
{
    const int wid  = threadIdx.x >> 6;       // 0..3
    const int lane = threadIdx.x & 63;
    const int half = wid & 1;                // which half of the row this wave scans
    int row = blockIdx.x * 2 + (wid >> 1);
    if (row >= Bsz) row = Bsz - 1;           // duplicate work at edge; same value written

    const float* __restrict__ yp = y_pred + (size_t)row * C;
    const float* __restrict__ yt = y_true + (size_t)row * C;

    // ---- vectorized dual argmax, 128 threads per row, stride 128 ----
    float bp = -FLT_MAX; int bip = 0;
    float bt = -FLT_MAX; int bit_ = 0;
    const int C4 = C >> 2;                   // 682
    const float4* __restrict__ yp4 = (const float4*)yp;
    const float4* __restrict__ yt4 = (const float4*)yt;

    for (int i = half * 64 + lane; i < C4; i += 128) {
        float4 v = yp4[i];
        float4 w = yt4[i];
        int base = i << 2;
        if (v.x > bp) { bp = v.x; bip = base + 0; }
        if (v.y > bp) { bp = v.y; bip = base + 1; }
        if (v.z > bp) { bp = v.z; bip = base + 2; }
        if (v.w > bp) { bp = v.w; bip = base + 3; }
        if (w.x > bt) { bt = w.x; bit_ = base + 0; }
        if (w.y > bt) { bt = w.y; bit_ = base + 1; }
        if (w.z > bt) { bt = w.z; bit_ = base + 2; }
        if (w.w > bt) { bt = w.w; bit_ = base + 3; }
    }
    for (int c = (C4 << 2) + half * 64 + lane; c < C; c += 128) {
        float v = yp[c]; if (v > bp) { bp = v; bip = c; }
        float w = yt[c]; if (w > bt) { bt = w; bit_ = c; }
    }

    // ---- butterfly reduce within wave ----
    for (int m = 1; m < 64; m <<= 1) {
        float ov = __shfl_xor(bp, m); int oi = __shfl_xor(bip, m);
        if (ov > bp || (ov == bp && oi < bip)) { bp = ov; bip = oi; }
        float ow = __shfl_xor(bt, m); int oj = __shfl_xor(bit_, m);
        if (ow > bt || (ow == bt && oj < bit_)) { bt = ow; bit_ = oj; }
    }

    // ---- merge the two waves of this row via LDS ----
    __shared__ float s_v[4][2];
    __shared__ int   s_i[4][2];
    if (lane == 0) {
        s_v[wid][0] = bp;  s_i[wid][0] = bip;
        s_v[wid][1] = bt;  s_i[wid][1] = bit_;
    }
    __syncthreads();
    {
        const int pw = wid ^ 1;
        float ov = s_v[pw][0]; int oi = s_i[pw][0];
        if (ov > bp || (ov == bp && oi < bip)) { bp = ov; bip = oi; }
        float ow = s_v[pw][1]; int oj = s_i[pw][1];
        if (ow > bt || (ow == bt && oj < bit_)) { bt = ow; bit_ = oj; }
    }

    // ---- tail: first wave of the pair only ----
    if (half == 0) {
        const int pred_top = bip;
        const int true_top = bit_;
        const int lp = path_len[pred_top];
        const int lt = path_len[true_top];
        const int lmin = lp < lt ? lp : lt;

        const int l = lane >> 3;             // level handled by this lane group
        const int j = lane & 7;              // element within sibling block
        float contrib = 0.0f;
        float e = 0.0f;
        int st = 0, sz = 0;
        if (l < lmin) {
            st = sib_start[true_top * D + l];
            sz = sib_size[true_top * D + l];
            if (j < sz) e = expf(yp[st + j]);   // in-block entries
        }
        // sum within the 8-lane group (xor masks stay inside 8-aligned groups)
        e += __shfl_xor(e, 1);
        e += __shfl_xor(e, 2);
        e += __shfl_xor(e, 4);
        if (l < lmin && j == 0) {
            // masked-out entries contribute exp(0)=1 each
            const float s = e + (float)(C - sz);
            const int tix = path_ids[true_top * D + l];
            const float ce = logf(s) - yp[tix];
            const float lw = expf(-DEPTH_PARAM * (float)(lt - l - 1));
            contrib = lw * ce;
        }
        // sum across group leaders (lanes 0,8,16,24,32,...)
        contrib += __shfl_xor(contrib, 8);
        contrib += __shfl_xor(contrib, 16);
        contrib += __shfl_xor(contrib, 32);

        if (lane == 0) {
            const float diff = fabsf((float)(lp - lt));
            row_total[row] = contrib * (LENGTH_PENALTY * diff) * class_weights[true_top];
        }
    }
}

// Deterministic final sum: one block reduces all row totals, writes mean.
__global__ __launch_bounds__(256) void final_reduce_kernel(
    const float* __restrict__ row_total, float* __restrict__ out, int Bsz)
{
    const int tid = threadIdx.x;
    float s = 0.0f;
    for (int i = tid; i < Bsz; i += 256) s += row_total[i];
    for (int m = 1; m < 64; m <<= 1) s += __shfl_xor(s, m);

    __shared__ float sw[4];
    const int lane = tid & 63, wid = tid >> 6;
    if (lane == 0) sw[wid] = s;
    __syncthreads();
    if (tid == 0) {
        float t = sw[0] + sw[1] + sw[2] + sw[3];
        out[0] = t / (float)Bsz;
    }
}

extern "C" void kernel_launch(void* const* d_in, const int* in_sizes, int n_in,
                              void* d_out, int out_size, void* d_ws, size_t ws_size,
                              hipStream_t stream) {
    const float* y_pred        = (const float*)d_in[0];
    const float* y_true        = (const float*)d_in[1];
    const float* class_weights = (const float*)d_in[2];
    const int*   path_ids      = (const int*)d_in[3];
    const int*   path_len      = (const int*)d_in[4];
    const int*   sib_start     = (const int*)d_in[5];
    const int*   sib_size      = (const int*)d_in[6];
    float* out = (float*)d_out;
    float* row_total = (float*)d_ws;   // B floats

    const int C = in_sizes[2];            // 2728
    const int D = in_sizes[3] / C;        // 5
    const int B = in_sizes[0] / C;        // 4096

    const int grid = (B + 1) / 2;         // 2 rows per block, 2 waves per row
    hier_row_kernel<<<grid, 256, 0, stream>>>(
        y_pred, y_true, class_weights, path_ids, path_len,
        sib_start, sib_size, row_total, C, D, B);
    final_reduce_kernel<<<1, 256, 0, stream>>>(row_total, out, B);
}